// Round 6
// baseline (274.947 us; speedup 1.0000x reference)
//
#include <hip/hip_runtime.h>

#define NB   64
#define LSEQ 8192
#define NW   8190
#define HD   90
#define AMPF 28.5f
#define NTILE 4

typedef _Float16 half8  __attribute__((ext_vector_type(8)));
typedef float    f32x16 __attribute__((ext_vector_type(16)));
typedef __fp16   fp16x2 __attribute__((ext_vector_type(2)));

union FragU { uint4 u; half8 h; };

__device__ __forceinline__ unsigned pk2(float a, float b) {
  fp16x2 v = __builtin_amdgcn_cvt_pkrtz(a, b);
  return __builtin_bit_cast(unsigned, v);
}
// packed ReLU on 2xfp16
__device__ __forceinline__ unsigned pkmax0(unsigned w) {
  unsigned r;
  asm("v_pk_max_f16 %0, %1, %2" : "=v"(r) : "v"(w), "v"(0u));
  return r;
}

// ---------------- weight fragment pre-pack (A-operand, swapped formulation) ----
// D[n][w] = sum_k W[k][n] * H[k][w].  A-frag layout (mfma_f32_32x32x16_f16):
//   lane l: row n = 32*t2 + (l&31);  k = 16*ks + 8*(l>>5) + i   (i = 0..7)
// ids: 0..2   layer1  (t2 = f, ks = 0; kin=7, k==7 -> b1)
//      3..74  layers2-5 (f = 3 + L*18 + t2*6 + ks; kin=90, k==90 -> bias)
//      75..80 layer6  (ks = f-75; nout=1: only row n==0 nonzero)
// Bias-propagation: for layers 1..5, A[k==kin][n==90] = 1.0 so that output
// row 90 == 1.0 for every window; it survives relu+pack exactly, and serves
// as the bias activation (k=90) for the next layer. No per-tile fixup needed.
__global__ void dnpu_pack(const float* __restrict__ W1, const float* __restrict__ b1,
                          const float* __restrict__ W2, const float* __restrict__ b2,
                          const float* __restrict__ W3, const float* __restrict__ b3,
                          const float* __restrict__ W4, const float* __restrict__ b4,
                          const float* __restrict__ W5, const float* __restrict__ b5,
                          const float* __restrict__ W6, const float* __restrict__ b6,
                          uint4* __restrict__ frags) {
  int tid = blockIdx.x * blockDim.x + threadIdx.x;
  if (tid >= 81 * 64) return;
  int f = tid >> 6, lane = tid & 63;
  int n = lane & 31, g = lane >> 5;
  const float* W; const float* bias; int t2, ks, kin, nout;
  if (f < 3) {
    W = W1; bias = b1; t2 = f; ks = 0; kin = 7; nout = HD;
  } else if (f < 75) {
    int q = f - 3; int L = q / 18; int r = q % 18;
    t2 = r / 6; ks = r % 6; kin = HD; nout = HD;
    W    = (L == 0) ? W2 : (L == 1) ? W3 : (L == 2) ? W4 : W5;
    bias = (L == 0) ? b2 : (L == 1) ? b3 : (L == 2) ? b4 : b5;
  } else {
    W = W6; bias = b6; t2 = 0; ks = f - 75; kin = HD; nout = 1;
  }
  int row = 32 * t2 + n;
  FragU u;
#pragma unroll
  for (int i = 0; i < 8; ++i) {
    int k = 16 * ks + 8 * g + i;
    float val = 0.f;
    if (row < nout) {
      if (k < kin)       val = W[k * nout + row];
      else if (k == kin) val = bias[row];
    }
    if (row == HD && k == kin && f < 75) val = 1.0f;  // bias-propagation row
    u.h[i] = (_Float16)val;
  }
  frags[f * 64 + lane] = u.u;
}

// ---- transition: acc (C-layout) -> next layer's B-frags, fully in-register ----
// C: lane l holds col w = l&31, row n = 32*t2 + (r&3) + 8*(r>>2) + 4*(l>>5).
// B-frag[ks=2u+par]: lane l needs col w = l&31 (same lane!), k' = n = 16ks+8g+i.
// Pack n-consecutive fp16 pairs (ReLU via pk_max post-pack), then one
// permlane32_swap per word pair so each lane holds its full i0..7 run.
__device__ __forceinline__ void transition(const f32x16 (&acc)[3], uint4 (&Bt)[6]) {
  unsigned P0[3][4], P1[3][4];
#pragma unroll
  for (int u = 0; u < 3; ++u) {
#pragma unroll
    for (int q = 0; q < 4; ++q) {
      P0[u][q] = pkmax0(pk2(acc[u][4 * q + 0], acc[u][4 * q + 1]));
      P1[u][q] = pkmax0(pk2(acc[u][4 * q + 2], acc[u][4 * q + 3]));
    }
  }
#pragma unroll
  for (int u = 0; u < 3; ++u) {
#pragma unroll
    for (int par = 0; par < 2; ++par) {
      unsigned w0 = P0[u][2 * par], w2 = P0[u][2 * par + 1];
      unsigned w1 = P1[u][2 * par], w3 = P1[u][2 * par + 1];
      asm("v_permlane32_swap_b32 %0, %1" : "+v"(w0), "+v"(w2));
      asm("v_permlane32_swap_b32 %0, %1" : "+v"(w1), "+v"(w3));
      Bt[2 * u + par] = make_uint4(w0, w1, w2, w3);
    }
  }
}

// ---------------- main kernel ----------------
__global__ __launch_bounds__(256, 4)
void dnpu_mfma(const float* __restrict__ x, const float* __restrict__ cv,
               const uint4* __restrict__ frags, float* __restrict__ out) {
  __shared__ uint4 lfr[36 * 64];             // layers 2-3 frags only, 36,864 B
  const int tid  = threadIdx.x;
  const int lane = tid & 63, wid = tid >> 6;
  const int g = lane >> 5, c = lane & 31;
  const int b = blockIdx.y;

  // stage layers 2-3 weight frags to LDS once per block
  for (int i = tid; i < 36 * 64; i += 256) lfr[i] = frags[192 + i];
  __syncthreads();

  const float c0 = cv[0], c1 = cv[1], c2 = cv[2], c3 = cv[3];
  const float* xr = x + (size_t)b * LSEQ;
  const int rowbase0 = blockIdx.x * 512 + wid * 128;

  uint4 Bw[NTILE][6];   // per-tile activation B-frags (current layer's input)

  // ---- layer 1: K padded to 16; g=0 lanes hold [c0,c1,x0,x1,x2,c2,c3,1] ----
  {
    FragU Af[3];
#pragma unroll
    for (int t2 = 0; t2 < 3; ++t2) Af[t2].u = frags[t2 * 64 + lane];
#pragma unroll
    for (int t = 0; t < NTILE; ++t) {
      const int w  = rowbase0 + t * 32 + c;
      const int xi = (w < LSEQ - 3) ? w : (LSEQ - 3);
      const float x0 = xr[xi], x1 = xr[xi + 1], x2 = xr[xi + 2];
      half8 B1;
#pragma unroll
      for (int i = 0; i < 8; ++i) B1[i] = (_Float16)0.f;
      if (g == 0) {
        B1[0] = (_Float16)c0; B1[1] = (_Float16)c1;
        B1[2] = (_Float16)x0; B1[3] = (_Float16)x1; B1[4] = (_Float16)x2;
        B1[5] = (_Float16)c2; B1[6] = (_Float16)c3; B1[7] = (_Float16)1.0f;
      }
      f32x16 acc[3];
#pragma unroll
      for (int t2 = 0; t2 < 3; ++t2)
        acc[t2] = __builtin_amdgcn_mfma_f32_32x32x16_f16(Af[t2].h, B1, (f32x16)(0.f), 0, 0, 0);
      transition(acc, Bw[t]);
    }
  }

  // ---- layers 2..5: L=0,1 frags from LDS; L=2,3 from global (L2-resident) ----
#pragma unroll 1
  for (int L = 0; L < 4; ++L) {
    FragU Af[18];
    if (L < 2) {
#pragma unroll
      for (int j = 0; j < 18; ++j) Af[j].u = lfr[(L * 18 + j) * 64 + lane];
    } else {
#pragma unroll
      for (int j = 0; j < 18; ++j) Af[j].u = frags[(3 + L * 18 + j) * 64 + lane];
    }
#pragma unroll
    for (int t = 0; t < NTILE; ++t) {
      f32x16 acc[3];
#pragma unroll
      for (int t2 = 0; t2 < 3; ++t2) {
        f32x16 a = (f32x16)(0.f);
#pragma unroll
        for (int ks = 0; ks < 6; ++ks)
          a = __builtin_amdgcn_mfma_f32_32x32x16_f16(
                Af[t2 * 6 + ks].h, __builtin_bit_cast(half8, Bw[t][ks]), a, 0, 0, 0);
        acc[t2] = a;
      }
      transition(acc, Bw[t]);
    }
  }

  // ---- layer 6: 96 -> 1 (row 0 of one n-tile), then * AMP ----
  {
    FragU Af[6];
#pragma unroll
    for (int ks = 0; ks < 6; ++ks) Af[ks].u = frags[(75 + ks) * 64 + lane];
#pragma unroll
    for (int t = 0; t < NTILE; ++t) {
      f32x16 a = (f32x16)(0.f);
#pragma unroll
      for (int ks = 0; ks < 6; ++ks)
        a = __builtin_amdgcn_mfma_f32_32x32x16_f16(
              Af[ks].h, __builtin_bit_cast(half8, Bw[t][ks]), a, 0, 0, 0);
      if (g == 0) {
        const int row = rowbase0 + t * 32 + c;
        if (row < NW) out[(size_t)b * NW + row] = a[0] * AMPF;
      }
    }
  }
}

extern "C" void kernel_launch(void* const* d_in, const int* in_sizes, int n_in,
                              void* d_out, int out_size, void* d_ws, size_t ws_size,
                              hipStream_t stream) {
  const float* x  = (const float*)d_in[0];
  const float* cv = (const float*)d_in[1];
  const float* W1 = (const float*)d_in[2];
  const float* b1 = (const float*)d_in[3];
  const float* W2 = (const float*)d_in[4];
  const float* b2 = (const float*)d_in[5];
  const float* W3 = (const float*)d_in[6];
  const float* b3 = (const float*)d_in[7];
  const float* W4 = (const float*)d_in[8];
  const float* b4 = (const float*)d_in[9];
  const float* W5 = (const float*)d_in[10];
  const float* b5 = (const float*)d_in[11];
  const float* W6 = (const float*)d_in[12];
  const float* b6 = (const float*)d_in[13];
  float* out = (float*)d_out;
  uint4* frags = (uint4*)d_ws;   // 81 * 64 * 16 B = 82,944 B

  hipLaunchKernelGGL(dnpu_pack, dim3(21), dim3(256), 0, stream,
                     W1, b1, W2, b2, W3, b3, W4, b4, W5, b5, W6, b6, frags);
  hipLaunchKernelGGL(dnpu_mfma, dim3(16, NB), dim3(256), 0, stream,
                     x, cv, frags, out);
}

// Round 7
// 53.338 us; speedup vs baseline: 5.1548x; 5.1548x over previous
//
#include <hip/hip_runtime.h>

#define NB   64
#define LSEQ 8192
#define NW   8190
#define HD   90
#define AMPF 28.5f
#define NTILE 4

typedef _Float16 half8  __attribute__((ext_vector_type(8)));
typedef float    f32x16 __attribute__((ext_vector_type(16)));
typedef __fp16   fp16x2 __attribute__((ext_vector_type(2)));

union FragU { uint4 u; half8 h; };

__device__ __forceinline__ unsigned pk2(float a, float b) {
  fp16x2 v = __builtin_amdgcn_cvt_pkrtz(a, b);
  return __builtin_bit_cast(unsigned, v);
}
// packed ReLU on 2xfp16
__device__ __forceinline__ unsigned pkmax0(unsigned w) {
  unsigned r;
  asm("v_pk_max_f16 %0, %1, %2" : "=v"(r) : "v"(w), "v"(0u));
  return r;
}

// ---------------- weight fragment pre-pack (A-operand, swapped formulation) ----
// D[n][w] = sum_k W[k][n] * H[k][w].  A-frag layout (mfma_f32_32x32x16_f16):
//   lane l: row n = 32*t2 + (l&31);  k = 16*ks + 8*(l>>5) + i   (i = 0..7)
// ids: 0..2   layer1  (t2 = f, ks = 0; kin=7, k==7 -> b1)
//      3..74  layers2-5 (f = 3 + L*18 + t2*6 + ks; kin=90, k==90 -> bias)
//      75..80 layer6  (ks = f-75; nout=1: only row n==0 nonzero)
// Bias-propagation: for layers 1..5, A[k==kin][n==90] = 1.0 so that output
// row 90 == 1.0 for every window; it survives relu+pack exactly, and serves
// as the bias activation (k=90) for the next layer. No per-tile fixup needed.
__global__ void dnpu_pack(const float* __restrict__ W1, const float* __restrict__ b1,
                          const float* __restrict__ W2, const float* __restrict__ b2,
                          const float* __restrict__ W3, const float* __restrict__ b3,
                          const float* __restrict__ W4, const float* __restrict__ b4,
                          const float* __restrict__ W5, const float* __restrict__ b5,
                          const float* __restrict__ W6, const float* __restrict__ b6,
                          uint4* __restrict__ frags) {
  int tid = blockIdx.x * blockDim.x + threadIdx.x;
  if (tid >= 81 * 64) return;
  int f = tid >> 6, lane = tid & 63;
  int n = lane & 31, g = lane >> 5;
  const float* W; const float* bias; int t2, ks, kin, nout;
  if (f < 3) {
    W = W1; bias = b1; t2 = f; ks = 0; kin = 7; nout = HD;
  } else if (f < 75) {
    int q = f - 3; int L = q / 18; int r = q % 18;
    t2 = r / 6; ks = r % 6; kin = HD; nout = HD;
    W    = (L == 0) ? W2 : (L == 1) ? W3 : (L == 2) ? W4 : W5;
    bias = (L == 0) ? b2 : (L == 1) ? b3 : (L == 2) ? b4 : b5;
  } else {
    W = W6; bias = b6; t2 = 0; ks = f - 75; kin = HD; nout = 1;
  }
  int row = 32 * t2 + n;
  FragU u;
#pragma unroll
  for (int i = 0; i < 8; ++i) {
    int k = 16 * ks + 8 * g + i;
    float val = 0.f;
    if (row < nout) {
      if (k < kin)       val = W[k * nout + row];
      else if (k == kin) val = bias[row];
    }
    if (row == HD && k == kin && f < 75) val = 1.0f;  // bias-propagation row
    u.h[i] = (_Float16)val;
  }
  frags[f * 64 + lane] = u.u;
}

// ---- transition: acc (C-layout) -> next layer's B-frags, fully in-register ----
// C: lane l holds col w = l&31, row n = 32*t2 + (r&3) + 8*(r>>2) + 4*(l>>5).
// B-frag[ks=2u+par]: lane l needs col w = l&31 (same lane!), k' = n = 16ks+8g+i.
// Pack n-consecutive fp16 pairs (ReLU via pk_max post-pack), then one
// permlane32_swap per word pair so each lane holds its full i0..7 run.
__device__ __forceinline__ void transition(const f32x16 (&acc)[3], uint4 (&Bt)[6]) {
  unsigned P0[3][4], P1[3][4];
#pragma unroll
  for (int u = 0; u < 3; ++u) {
#pragma unroll
    for (int q = 0; q < 4; ++q) {
      P0[u][q] = pkmax0(pk2(acc[u][4 * q + 0], acc[u][4 * q + 1]));
      P1[u][q] = pkmax0(pk2(acc[u][4 * q + 2], acc[u][4 * q + 3]));
    }
  }
#pragma unroll
  for (int u = 0; u < 3; ++u) {
#pragma unroll
    for (int par = 0; par < 2; ++par) {
      unsigned w0 = P0[u][2 * par], w2 = P0[u][2 * par + 1];
      unsigned w1 = P1[u][2 * par], w3 = P1[u][2 * par + 1];
      asm("v_permlane32_swap_b32 %0, %1" : "+v"(w0), "+v"(w2));
      asm("v_permlane32_swap_b32 %0, %1" : "+v"(w1), "+v"(w3));
      Bt[2 * u + par] = make_uint4(w0, w1, w2, w3);
    }
  }
}

// ---------------- main kernel ----------------
// NOTE: min-waves arg MUST stay <= 2: requesting 4 caps VGPRs at 64 on this
// MFMA kernel (measured R5/R6) and spills ~1.1 GB of scratch. Occupancy comes
// from the 36.9 KB LDS footprint (4 blocks/CU) at natural ~116 VGPR.
__global__ __launch_bounds__(256, 2)
void dnpu_mfma(const float* __restrict__ x, const float* __restrict__ cv,
               const uint4* __restrict__ frags, float* __restrict__ out) {
  __shared__ uint4 lfr[36 * 64];             // layers 2-3 frags only, 36,864 B
  const int tid  = threadIdx.x;
  const int lane = tid & 63, wid = tid >> 6;
  const int g = lane >> 5, c = lane & 31;
  const int b = blockIdx.y;

  // stage layers 2-3 weight frags to LDS once per block
  for (int i = tid; i < 36 * 64; i += 256) lfr[i] = frags[192 + i];
  __syncthreads();

  const float c0 = cv[0], c1 = cv[1], c2 = cv[2], c3 = cv[3];
  const float* xr = x + (size_t)b * LSEQ;
  const int rowbase0 = blockIdx.x * 512 + wid * 128;

  uint4 Bw[NTILE][6];   // per-tile activation B-frags (current layer's input)

  // ---- layer 1: K padded to 16; g=0 lanes hold [c0,c1,x0,x1,x2,c2,c3,1] ----
  {
    FragU Af[3];
#pragma unroll
    for (int t2 = 0; t2 < 3; ++t2) Af[t2].u = frags[t2 * 64 + lane];
#pragma unroll
    for (int t = 0; t < NTILE; ++t) {
      const int w  = rowbase0 + t * 32 + c;
      const int xi = (w < LSEQ - 3) ? w : (LSEQ - 3);
      const float x0 = xr[xi], x1 = xr[xi + 1], x2 = xr[xi + 2];
      half8 B1;
#pragma unroll
      for (int i = 0; i < 8; ++i) B1[i] = (_Float16)0.f;
      if (g == 0) {
        B1[0] = (_Float16)c0; B1[1] = (_Float16)c1;
        B1[2] = (_Float16)x0; B1[3] = (_Float16)x1; B1[4] = (_Float16)x2;
        B1[5] = (_Float16)c2; B1[6] = (_Float16)c3; B1[7] = (_Float16)1.0f;
      }
      f32x16 acc[3];
#pragma unroll
      for (int t2 = 0; t2 < 3; ++t2)
        acc[t2] = __builtin_amdgcn_mfma_f32_32x32x16_f16(Af[t2].h, B1, (f32x16)(0.f), 0, 0, 0);
      transition(acc, Bw[t]);
    }
  }

  // ---- layers 2..5: L=0,1 frags from LDS; L=2,3 from global (L2-resident) ----
#pragma unroll 1
  for (int L = 0; L < 4; ++L) {
    FragU Af[18];
    if (L < 2) {
#pragma unroll
      for (int j = 0; j < 18; ++j) Af[j].u = lfr[(L * 18 + j) * 64 + lane];
    } else {
#pragma unroll
      for (int j = 0; j < 18; ++j) Af[j].u = frags[(3 + L * 18 + j) * 64 + lane];
    }
#pragma unroll
    for (int t = 0; t < NTILE; ++t) {
      f32x16 acc[3];
#pragma unroll
      for (int t2 = 0; t2 < 3; ++t2) {
        f32x16 a = (f32x16)(0.f);
#pragma unroll
        for (int ks = 0; ks < 6; ++ks)
          a = __builtin_amdgcn_mfma_f32_32x32x16_f16(
                Af[t2 * 6 + ks].h, __builtin_bit_cast(half8, Bw[t][ks]), a, 0, 0, 0);
        acc[t2] = a;
      }
      transition(acc, Bw[t]);
    }
  }

  // ---- layer 6: 96 -> 1 (row 0 of one n-tile), then * AMP ----
  {
    FragU Af[6];
#pragma unroll
    for (int ks = 0; ks < 6; ++ks) Af[ks].u = frags[(75 + ks) * 64 + lane];
#pragma unroll
    for (int t = 0; t < NTILE; ++t) {
      f32x16 a = (f32x16)(0.f);
#pragma unroll
      for (int ks = 0; ks < 6; ++ks)
        a = __builtin_amdgcn_mfma_f32_32x32x16_f16(
              Af[ks].h, __builtin_bit_cast(half8, Bw[t][ks]), a, 0, 0, 0);
      if (g == 0) {
        const int row = rowbase0 + t * 32 + c;
        if (row < NW) out[(size_t)b * NW + row] = a[0] * AMPF;
      }
    }
  }
}

extern "C" void kernel_launch(void* const* d_in, const int* in_sizes, int n_in,
                              void* d_out, int out_size, void* d_ws, size_t ws_size,
                              hipStream_t stream) {
  const float* x  = (const float*)d_in[0];
  const float* cv = (const float*)d_in[1];
  const float* W1 = (const float*)d_in[2];
  const float* b1 = (const float*)d_in[3];
  const float* W2 = (const float*)d_in[4];
  const float* b2 = (const float*)d_in[5];
  const float* W3 = (const float*)d_in[6];
  const float* b3 = (const float*)d_in[7];
  const float* W4 = (const float*)d_in[8];
  const float* b4 = (const float*)d_in[9];
  const float* W5 = (const float*)d_in[10];
  const float* b5 = (const float*)d_in[11];
  const float* W6 = (const float*)d_in[12];
  const float* b6 = (const float*)d_in[13];
  float* out = (float*)d_out;
  uint4* frags = (uint4*)d_ws;   // 81 * 64 * 16 B = 82,944 B

  hipLaunchKernelGGL(dnpu_pack, dim3(21), dim3(256), 0, stream,
                     W1, b1, W2, b2, W3, b3, W4, b4, W5, b5, W6, b6, frags);
  hipLaunchKernelGGL(dnpu_mfma, dim3(16, NB), dim3(256), 0, stream,
                     x, cv, frags, out);
}

// Round 8
// 48.509 us; speedup vs baseline: 5.6680x; 1.0996x over previous
//
#include <hip/hip_runtime.h>

#define NB   64
#define LSEQ 8192
#define NW   8190
#define HD   90
#define AMPF 28.5f
#define NTILE 2

typedef _Float16 half8  __attribute__((ext_vector_type(8)));
typedef float    f32x16 __attribute__((ext_vector_type(16)));
typedef __fp16   fp16x2 __attribute__((ext_vector_type(2)));

union FragU { uint4 u; half8 h; };

__device__ __forceinline__ unsigned pk2(float a, float b) {
  fp16x2 v = __builtin_amdgcn_cvt_pkrtz(a, b);
  return __builtin_bit_cast(unsigned, v);
}
// packed ReLU on 2xfp16
__device__ __forceinline__ unsigned pkmax0(unsigned w) {
  unsigned r;
  asm("v_pk_max_f16 %0, %1, %2" : "=v"(r) : "v"(w), "v"(0u));
  return r;
}

// ---------------- weight fragment pre-pack (A-operand, swapped formulation) ----
// D[n][w] = sum_k W[k][n] * H[k][w].  A-frag layout (mfma_f32_32x32x16_f16):
//   lane l: row n = 32*t2 + (l&31);  k = 16*ks + 8*(l>>5) + i   (i = 0..7)
// ids: 0..2   layer1  (t2 = f, ks = 0; kin=7, k==7 -> b1)
//      3..74  layers2-5 (f = 3 + L*18 + t2*6 + ks; kin=90, k==90 -> bias)
//      75..80 layer6  (ks = f-75; nout=1: only row n==0 nonzero)
// Bias-propagation: for layers 1..5, A[k==kin][n==90] = 1.0 so that output
// row 90 == 1.0 for every window; it survives relu+pack exactly, and serves
// as the bias activation (k=90) for the next layer. No per-tile fixup needed.
__global__ void dnpu_pack(const float* __restrict__ W1, const float* __restrict__ b1,
                          const float* __restrict__ W2, const float* __restrict__ b2,
                          const float* __restrict__ W3, const float* __restrict__ b3,
                          const float* __restrict__ W4, const float* __restrict__ b4,
                          const float* __restrict__ W5, const float* __restrict__ b5,
                          const float* __restrict__ W6, const float* __restrict__ b6,
                          uint4* __restrict__ frags) {
  int tid = blockIdx.x * blockDim.x + threadIdx.x;
  if (tid >= 81 * 64) return;
  int f = tid >> 6, lane = tid & 63;
  int n = lane & 31, g = lane >> 5;
  const float* W; const float* bias; int t2, ks, kin, nout;
  if (f < 3) {
    W = W1; bias = b1; t2 = f; ks = 0; kin = 7; nout = HD;
  } else if (f < 75) {
    int q = f - 3; int L = q / 18; int r = q % 18;
    t2 = r / 6; ks = r % 6; kin = HD; nout = HD;
    W    = (L == 0) ? W2 : (L == 1) ? W3 : (L == 2) ? W4 : W5;
    bias = (L == 0) ? b2 : (L == 1) ? b3 : (L == 2) ? b4 : b5;
  } else {
    W = W6; bias = b6; t2 = 0; ks = f - 75; kin = HD; nout = 1;
  }
  int row = 32 * t2 + n;
  FragU u;
#pragma unroll
  for (int i = 0; i < 8; ++i) {
    int k = 16 * ks + 8 * g + i;
    float val = 0.f;
    if (row < nout) {
      if (k < kin)       val = W[k * nout + row];
      else if (k == kin) val = bias[row];
    }
    if (row == HD && k == kin && f < 75) val = 1.0f;  // bias-propagation row
    u.h[i] = (_Float16)val;
  }
  frags[f * 64 + lane] = u.u;
}

// ---- transition: acc (C-layout) -> next layer's B-frags, fully in-register ----
// C: lane l holds col w = l&31, row n = 32*t2 + (r&3) + 8*(r>>2) + 4*(l>>5).
// B-frag[ks=2u+par]: lane l needs col w = l&31 (same lane!), k' = n = 16ks+8g+i.
// Pack n-consecutive fp16 pairs (ReLU via pk_max post-pack), then one
// permlane32_swap per word pair so each lane holds its full i0..7 run.
__device__ __forceinline__ void transition(const f32x16 (&acc)[3], uint4 (&Bt)[6]) {
  unsigned P0[3][4], P1[3][4];
#pragma unroll
  for (int u = 0; u < 3; ++u) {
#pragma unroll
    for (int q = 0; q < 4; ++q) {
      P0[u][q] = pkmax0(pk2(acc[u][4 * q + 0], acc[u][4 * q + 1]));
      P1[u][q] = pkmax0(pk2(acc[u][4 * q + 2], acc[u][4 * q + 3]));
    }
  }
#pragma unroll
  for (int u = 0; u < 3; ++u) {
#pragma unroll
    for (int par = 0; par < 2; ++par) {
      unsigned w0 = P0[u][2 * par], w2 = P0[u][2 * par + 1];
      unsigned w1 = P1[u][2 * par], w3 = P1[u][2 * par + 1];
      asm("v_permlane32_swap_b32 %0, %1" : "+v"(w0), "+v"(w2));
      asm("v_permlane32_swap_b32 %0, %1" : "+v"(w1), "+v"(w3));
      Bt[2 * u + par] = make_uint4(w0, w1, w2, w3);
    }
  }
}

// one hidden 96x96 layer: A-frags streamed one-at-a-time from LDS (low reg use)
__device__ __forceinline__ void hidden_layer(const uint4* __restrict__ src, int lane,
                                             uint4 (&Bw)[NTILE][6]) {
#pragma unroll
  for (int t = 0; t < NTILE; ++t) {
    f32x16 acc[3];
#pragma unroll
    for (int u = 0; u < 3; ++u) {
      f32x16 a = (f32x16)(0.f);
#pragma unroll
      for (int ks = 0; ks < 6; ++ks) {
        FragU Af; Af.u = src[(u * 6 + ks) * 64 + lane];
        a = __builtin_amdgcn_mfma_f32_32x32x16_f16(
              Af.h, __builtin_bit_cast(half8, Bw[t][ks]), a, 0, 0, 0);
      }
      acc[u] = a;
    }
    transition(acc, Bw[t]);
  }
}

// ---------------- main kernel ----------------
// NOTE: min-waves arg MUST stay <= 2: requesting 4 caps VGPRs at 64 on this
// MFMA kernel (measured R5/R6) and spills ~1.1 GB of scratch. Residency is
// register-limited; this version targets ~150 total regs -> 3 waves/SIMD.
__global__ __launch_bounds__(256, 2)
void dnpu_mfma(const float* __restrict__ x, const float* __restrict__ cv,
               const uint4* __restrict__ frags, float* __restrict__ out) {
  __shared__ uint4 lfr[2][18 * 64];          // 2 x 18,432 B = 36,864 B
  const int tid  = threadIdx.x;
  const int lane = tid & 63, wid = tid >> 6;
  const int g = lane >> 5, c = lane & 31;
  const int b = blockIdx.y;

  // stage L2 -> buf0, L3 -> buf1
  for (int i = tid; i < 18 * 64; i += 256) {
    lfr[0][i] = frags[3 * 64 + i];
    lfr[1][i] = frags[21 * 64 + i];
  }
  __syncthreads();

  const float c0 = cv[0], c1 = cv[1], c2 = cv[2], c3 = cv[3];
  const float* xr = x + (size_t)b * LSEQ;
  const int rowbase0 = blockIdx.x * (NTILE * 32 * 4) + wid * (NTILE * 32);

  uint4 Bw[NTILE][6];   // per-tile activation B-frags (current layer's input)

  // ---- layer 1: K padded to 16; g=0 lanes hold [c0,c1,x0,x1,x2,c2,c3,1] ----
#pragma unroll
  for (int t = 0; t < NTILE; ++t) {
    const int w  = rowbase0 + t * 32 + c;
    const int xi = (w < LSEQ - 3) ? w : (LSEQ - 3);
    const float x0 = xr[xi], x1 = xr[xi + 1], x2 = xr[xi + 2];
    half8 B1;
#pragma unroll
    for (int i = 0; i < 8; ++i) B1[i] = (_Float16)0.f;
    if (g == 0) {
      B1[0] = (_Float16)c0; B1[1] = (_Float16)c1;
      B1[2] = (_Float16)x0; B1[3] = (_Float16)x1; B1[4] = (_Float16)x2;
      B1[5] = (_Float16)c2; B1[6] = (_Float16)c3; B1[7] = (_Float16)1.0f;
    }
    f32x16 acc[3];
#pragma unroll
    for (int t2 = 0; t2 < 3; ++t2) {
      FragU Af; Af.u = frags[t2 * 64 + lane];
      acc[t2] = __builtin_amdgcn_mfma_f32_32x32x16_f16(Af.h, B1, (f32x16)(0.f), 0, 0, 0);
    }
    transition(acc, Bw[t]);
  }

  // ---- layer 2 (buf0), then restage L4 over buf0; layer 3 (buf1), restage L5 ----
  hidden_layer(&lfr[0][0], lane, Bw);        // L2
  __syncthreads();                           // all waves done reading buf0
  for (int i = tid; i < 18 * 64; i += 256) lfr[0][i] = frags[39 * 64 + i];  // L4
  __syncthreads();
  hidden_layer(&lfr[1][0], lane, Bw);        // L3
  __syncthreads();                           // all waves done reading buf1
  for (int i = tid; i < 18 * 64; i += 256) lfr[1][i] = frags[57 * 64 + i];  // L5
  __syncthreads();
  hidden_layer(&lfr[0][0], lane, Bw);        // L4
  hidden_layer(&lfr[1][0], lane, Bw);        // L5

  // ---- layer 6: 96 -> 1 (row 0 of n-tile 0), then * AMP ----
#pragma unroll
  for (int t = 0; t < NTILE; ++t) {
    f32x16 a = (f32x16)(0.f);
#pragma unroll
    for (int ks = 0; ks < 6; ++ks) {
      FragU Af; Af.u = frags[(75 + ks) * 64 + lane];
      a = __builtin_amdgcn_mfma_f32_32x32x16_f16(
            Af.h, __builtin_bit_cast(half8, Bw[t][ks]), a, 0, 0, 0);
    }
    if (g == 0) {
      const int row = rowbase0 + t * 32 + c;
      if (row < NW) out[(size_t)b * NW + row] = a[0] * AMPF;
    }
  }
}

extern "C" void kernel_launch(void* const* d_in, const int* in_sizes, int n_in,
                              void* d_out, int out_size, void* d_ws, size_t ws_size,
                              hipStream_t stream) {
  const float* x  = (const float*)d_in[0];
  const float* cv = (const float*)d_in[1];
  const float* W1 = (const float*)d_in[2];
  const float* b1 = (const float*)d_in[3];
  const float* W2 = (const float*)d_in[4];
  const float* b2 = (const float*)d_in[5];
  const float* W3 = (const float*)d_in[6];
  const float* b3 = (const float*)d_in[7];
  const float* W4 = (const float*)d_in[8];
  const float* b4 = (const float*)d_in[9];
  const float* W5 = (const float*)d_in[10];
  const float* b5 = (const float*)d_in[11];
  const float* W6 = (const float*)d_in[12];
  const float* b6 = (const float*)d_in[13];
  float* out = (float*)d_out;
  uint4* frags = (uint4*)d_ws;   // 81 * 64 * 16 B = 82,944 B

  hipLaunchKernelGGL(dnpu_pack, dim3(21), dim3(256), 0, stream,
                     W1, b1, W2, b2, W3, b3, W4, b4, W5, b5, W6, b6, frags);
  // 8192 windows covered: 32 blocks x (4 waves * 64 windows)
  hipLaunchKernelGGL(dnpu_mfma, dim3(32, NB), dim3(256), 0, stream,
                     x, cv, frags, out);
}

// Round 9
// 48.104 us; speedup vs baseline: 5.7157x; 1.0084x over previous
//
#include <hip/hip_runtime.h>

#define NB   64
#define LSEQ 8192
#define NW   8190
#define HD   90
#define AMPF 28.5f
#define NTILE 2

typedef _Float16 half8  __attribute__((ext_vector_type(8)));
typedef float    f32x16 __attribute__((ext_vector_type(16)));
typedef __fp16   fp16x2 __attribute__((ext_vector_type(2)));

union FragU { uint4 u; half8 h; };

__device__ __forceinline__ unsigned pk2(float a, float b) {
  fp16x2 v = __builtin_amdgcn_cvt_pkrtz(a, b);
  return __builtin_bit_cast(unsigned, v);
}
// packed ReLU on 2xfp16
__device__ __forceinline__ unsigned pkmax0(unsigned w) {
  unsigned r;
  asm("v_pk_max_f16 %0, %1, %2" : "=v"(r) : "v"(w), "v"(0u));
  return r;
}

// ---------------- weight fragment pre-pack (A-operand, swapped formulation) ----
// D[n][w] = sum_k W[k][n] * H[k][w].  A-frag layout (mfma_f32_32x32x16_f16):
//   lane l: row n = 32*t2 + (l&31);  k = 16*ks + 8*(l>>5) + i   (i = 0..7)
// ids: 0..2   layer1  (t2 = f, ks = 0; kin=7, k==7 -> b1)
//      3..74  layers2-5 (f = 3 + L*18 + t2*6 + ks; kin=90, k==90 -> bias)
//      75..80 layer6  (ks = f-75; nout=1: only row n==0 nonzero)
// Bias-propagation: for layers 1..5, A[k==kin][n==90] = 1.0 so that output
// row 90 == 1.0 for every window; it survives relu+pack exactly, and serves
// as the bias activation (k=90) for the next layer. No per-tile fixup needed.
__global__ void dnpu_pack(const float* __restrict__ W1, const float* __restrict__ b1,
                          const float* __restrict__ W2, const float* __restrict__ b2,
                          const float* __restrict__ W3, const float* __restrict__ b3,
                          const float* __restrict__ W4, const float* __restrict__ b4,
                          const float* __restrict__ W5, const float* __restrict__ b5,
                          const float* __restrict__ W6, const float* __restrict__ b6,
                          uint4* __restrict__ frags) {
  int tid = blockIdx.x * blockDim.x + threadIdx.x;
  if (tid >= 81 * 64) return;
  int f = tid >> 6, lane = tid & 63;
  int n = lane & 31, g = lane >> 5;
  const float* W; const float* bias; int t2, ks, kin, nout;
  if (f < 3) {
    W = W1; bias = b1; t2 = f; ks = 0; kin = 7; nout = HD;
  } else if (f < 75) {
    int q = f - 3; int L = q / 18; int r = q % 18;
    t2 = r / 6; ks = r % 6; kin = HD; nout = HD;
    W    = (L == 0) ? W2 : (L == 1) ? W3 : (L == 2) ? W4 : W5;
    bias = (L == 0) ? b2 : (L == 1) ? b3 : (L == 2) ? b4 : b5;
  } else {
    W = W6; bias = b6; t2 = 0; ks = f - 75; kin = HD; nout = 1;
  }
  int row = 32 * t2 + n;
  FragU u;
#pragma unroll
  for (int i = 0; i < 8; ++i) {
    int k = 16 * ks + 8 * g + i;
    float val = 0.f;
    if (row < nout) {
      if (k < kin)       val = W[k * nout + row];
      else if (k == kin) val = bias[row];
    }
    if (row == HD && k == kin && f < 75) val = 1.0f;  // bias-propagation row
    u.h[i] = (_Float16)val;
  }
  frags[f * 64 + lane] = u.u;
}

// ---- transition: acc (C-layout) -> next layer's B-frags, fully in-register ----
// C: lane l holds col w = l&31, row n = 32*t2 + (r&3) + 8*(r>>2) + 4*(l>>5).
// B-frag[ks=2u+par]: lane l needs col w = l&31 (same lane!), k' = n = 16ks+8g+i.
// Pack n-consecutive fp16 pairs (ReLU via pk_max post-pack), then one
// permlane32_swap per word pair so each lane holds its full i0..7 run.
__device__ __forceinline__ void transition(const f32x16 (&acc)[3], uint4 (&Bt)[6]) {
  unsigned P0[3][4], P1[3][4];
#pragma unroll
  for (int u = 0; u < 3; ++u) {
#pragma unroll
    for (int q = 0; q < 4; ++q) {
      P0[u][q] = pkmax0(pk2(acc[u][4 * q + 0], acc[u][4 * q + 1]));
      P1[u][q] = pkmax0(pk2(acc[u][4 * q + 2], acc[u][4 * q + 3]));
    }
  }
#pragma unroll
  for (int u = 0; u < 3; ++u) {
#pragma unroll
    for (int par = 0; par < 2; ++par) {
      unsigned w0 = P0[u][2 * par], w2 = P0[u][2 * par + 1];
      unsigned w1 = P1[u][2 * par], w3 = P1[u][2 * par + 1];
      asm("v_permlane32_swap_b32 %0, %1" : "+v"(w0), "+v"(w2));
      asm("v_permlane32_swap_b32 %0, %1" : "+v"(w1), "+v"(w3));
      Bt[2 * u + par] = make_uint4(w0, w1, w2, w3);
    }
  }
}

// one hidden 96x96 layer: A-frags streamed one-at-a-time from LDS (low reg use)
__device__ __forceinline__ void hidden_layer(const uint4* __restrict__ src, int lane,
                                             uint4 (&Bw)[NTILE][6]) {
#pragma unroll
  for (int t = 0; t < NTILE; ++t) {
    f32x16 acc[3];
#pragma unroll
    for (int u = 0; u < 3; ++u) {
      f32x16 a = (f32x16)(0.f);
#pragma unroll
      for (int ks = 0; ks < 6; ++ks) {
        FragU Af; Af.u = src[(u * 6 + ks) * 64 + lane];
        a = __builtin_amdgcn_mfma_f32_32x32x16_f16(
              Af.h, __builtin_bit_cast(half8, Bw[t][ks]), a, 0, 0, 0);
      }
      acc[u] = a;
    }
    transition(acc, Bw[t]);
  }
}

// ---------------- main kernel ----------------
// NOTE (measured R5/R6/R7/R8): min-waves in launch_bounds caps VGPR at
// 256/min_waves on this kernel; min=4 -> 64 regs -> 1.1 GB spill. Keep cap
// 128 >= 96 natural. 256-thread blocks pinned measured occupancy at ~17%
// regardless of LDS/VGPR; 512-thread blocks reached 39% (R5) -> use 512.
__global__ __launch_bounds__(512, 2)
void dnpu_mfma(const float* __restrict__ x, const float* __restrict__ cv,
               const uint4* __restrict__ frags, float* __restrict__ out) {
  __shared__ uint4 lfr[72 * 64];             // layers 2-5 frags, 73,728 B
  const int tid  = threadIdx.x;
  const int lane = tid & 63, wid = tid >> 6;
  const int g = lane >> 5, c = lane & 31;
  const int b = blockIdx.y;

  // stage layers 2-5 weight frags to LDS once per block (8 waves share them)
  for (int i = tid; i < 72 * 64; i += 512) lfr[i] = frags[3 * 64 + i];
  __syncthreads();

  const float c0 = cv[0], c1 = cv[1], c2 = cv[2], c3 = cv[3];
  const float* xr = x + (size_t)b * LSEQ;
  const int rowbase0 = blockIdx.x * (NTILE * 32 * 8) + wid * (NTILE * 32);

  uint4 Bw[NTILE][6];   // per-tile activation B-frags (current layer's input)

  // ---- layer 1: K padded to 16; g=0 lanes hold [c0,c1,x0,x1,x2,c2,c3,1] ----
#pragma unroll
  for (int t = 0; t < NTILE; ++t) {
    const int w  = rowbase0 + t * 32 + c;
    const int xi = (w < LSEQ - 3) ? w : (LSEQ - 3);
    const float x0 = xr[xi], x1 = xr[xi + 1], x2 = xr[xi + 2];
    half8 B1;
#pragma unroll
    for (int i = 0; i < 8; ++i) B1[i] = (_Float16)0.f;
    if (g == 0) {
      B1[0] = (_Float16)c0; B1[1] = (_Float16)c1;
      B1[2] = (_Float16)x0; B1[3] = (_Float16)x1; B1[4] = (_Float16)x2;
      B1[5] = (_Float16)c2; B1[6] = (_Float16)c3; B1[7] = (_Float16)1.0f;
    }
    f32x16 acc[3];
#pragma unroll
    for (int t2 = 0; t2 < 3; ++t2) {
      FragU Af; Af.u = frags[t2 * 64 + lane];
      acc[t2] = __builtin_amdgcn_mfma_f32_32x32x16_f16(Af.h, B1, (f32x16)(0.f), 0, 0, 0);
    }
    transition(acc, Bw[t]);
  }

  // ---- layers 2..5 from LDS ----
  hidden_layer(&lfr[0 * 18 * 64], lane, Bw);   // L2
  hidden_layer(&lfr[1 * 18 * 64], lane, Bw);   // L3
  hidden_layer(&lfr[2 * 18 * 64], lane, Bw);   // L4
  hidden_layer(&lfr[3 * 18 * 64], lane, Bw);   // L5

  // ---- layer 6: 96 -> 1 (row 0 of n-tile 0), then * AMP ----
#pragma unroll
  for (int t = 0; t < NTILE; ++t) {
    f32x16 a = (f32x16)(0.f);
#pragma unroll
    for (int ks = 0; ks < 6; ++ks) {
      FragU Af; Af.u = frags[(75 + ks) * 64 + lane];
      a = __builtin_amdgcn_mfma_f32_32x32x16_f16(
            Af.h, __builtin_bit_cast(half8, Bw[t][ks]), a, 0, 0, 0);
    }
    if (g == 0) {
      const int row = rowbase0 + t * 32 + c;
      if (row < NW) out[(size_t)b * NW + row] = a[0] * AMPF;
    }
  }
}

extern "C" void kernel_launch(void* const* d_in, const int* in_sizes, int n_in,
                              void* d_out, int out_size, void* d_ws, size_t ws_size,
                              hipStream_t stream) {
  const float* x  = (const float*)d_in[0];
  const float* cv = (const float*)d_in[1];
  const float* W1 = (const float*)d_in[2];
  const float* b1 = (const float*)d_in[3];
  const float* W2 = (const float*)d_in[4];
  const float* b2 = (const float*)d_in[5];
  const float* W3 = (const float*)d_in[6];
  const float* b3 = (const float*)d_in[7];
  const float* W4 = (const float*)d_in[8];
  const float* b4 = (const float*)d_in[9];
  const float* W5 = (const float*)d_in[10];
  const float* b5 = (const float*)d_in[11];
  const float* W6 = (const float*)d_in[12];
  const float* b6 = (const float*)d_in[13];
  float* out = (float*)d_out;
  uint4* frags = (uint4*)d_ws;   // 81 * 64 * 16 B = 82,944 B

  hipLaunchKernelGGL(dnpu_pack, dim3(21), dim3(256), 0, stream,
                     W1, b1, W2, b2, W3, b3, W4, b4, W5, b5, W6, b6, frags);
  // 8192 windows: 16 blocks x (8 waves * 64 windows)
  hipLaunchKernelGGL(dnpu_mfma, dim3(16, NB), dim3(512), 0, stream,
                     x, cv, frags, out);
}

// Round 10
// 46.595 us; speedup vs baseline: 5.9007x; 1.0324x over previous
//
#include <hip/hip_runtime.h>

#define NB   64
#define LSEQ 8192
#define NW   8190
#define HD   90
#define AMPF 28.5f
#define NTILE 2

typedef _Float16 half8  __attribute__((ext_vector_type(8)));
typedef float    f32x16 __attribute__((ext_vector_type(16)));
typedef __fp16   fp16x2 __attribute__((ext_vector_type(2)));

union FragU { uint4 u; half8 h; };

__device__ __forceinline__ unsigned pk2(float a, float b) {
  fp16x2 v = __builtin_amdgcn_cvt_pkrtz(a, b);
  return __builtin_bit_cast(unsigned, v);
}
// packed ReLU on 2xfp16
__device__ __forceinline__ unsigned pkmax0(unsigned w) {
  unsigned r;
  asm("v_pk_max_f16 %0, %1, %2" : "=v"(r) : "v"(w), "v"(0u));
  return r;
}

// ---------------- weight fragment pre-pack (A-operand, swapped formulation) ----
// D[n][w] = sum_k W[k][n] * H[k][w].  A-frag layout (mfma_f32_32x32x16_f16):
//   lane l: row n = 32*t2 + (l&31);  k = 16*ks + 8*(l>>5) + i   (i = 0..7)
// ids: 0..2   layer1  (t2 = f, ks = 0; kin=7, k==7 -> b1)
//      3..74  layers2-5 (f = 3 + L*18 + t2*6 + ks; kin=90, k==90 -> bias)
//      75..80 layer6  (ks = f-75; nout=1: only row n==0 nonzero)
// Bias-propagation: for layers 1..5, A[k==kin][n==90] = 1.0 so that output
// row 90 == 1.0 for every window; it survives relu+pack exactly, and serves
// as the bias activation (k=90) for the next layer. No per-tile fixup needed.
__global__ void dnpu_pack(const float* __restrict__ W1, const float* __restrict__ b1,
                          const float* __restrict__ W2, const float* __restrict__ b2,
                          const float* __restrict__ W3, const float* __restrict__ b3,
                          const float* __restrict__ W4, const float* __restrict__ b4,
                          const float* __restrict__ W5, const float* __restrict__ b5,
                          const float* __restrict__ W6, const float* __restrict__ b6,
                          uint4* __restrict__ frags) {
  int tid = blockIdx.x * blockDim.x + threadIdx.x;
  if (tid >= 81 * 64) return;
  int f = tid >> 6, lane = tid & 63;
  int n = lane & 31, g = lane >> 5;
  const float* W; const float* bias; int t2, ks, kin, nout;
  if (f < 3) {
    W = W1; bias = b1; t2 = f; ks = 0; kin = 7; nout = HD;
  } else if (f < 75) {
    int q = f - 3; int L = q / 18; int r = q % 18;
    t2 = r / 6; ks = r % 6; kin = HD; nout = HD;
    W    = (L == 0) ? W2 : (L == 1) ? W3 : (L == 2) ? W4 : W5;
    bias = (L == 0) ? b2 : (L == 1) ? b3 : (L == 2) ? b4 : b5;
  } else {
    W = W6; bias = b6; t2 = 0; ks = f - 75; kin = HD; nout = 1;
  }
  int row = 32 * t2 + n;
  FragU u;
#pragma unroll
  for (int i = 0; i < 8; ++i) {
    int k = 16 * ks + 8 * g + i;
    float val = 0.f;
    if (row < nout) {
      if (k < kin)       val = W[k * nout + row];
      else if (k == kin) val = bias[row];
    }
    if (row == HD && k == kin && f < 75) val = 1.0f;  // bias-propagation row
    u.h[i] = (_Float16)val;
  }
  frags[f * 64 + lane] = u.u;
}

// ---- per-u transition: one 32x96 acc slice -> two next-layer B-frags ----
// C: lane l holds col w = l&31, row n = 32*u + (r&3) + 8*(r>>2) + 4*(l>>5).
// B-frag[ks=2u+par]: lane l needs col w = l&31 (same lane), k' = n.
// Pack n-consecutive fp16 pairs (ReLU via pk_max post-pack), then one
// permlane32_swap per word pair so each lane holds its full i0..7 run.
__device__ __forceinline__ void trans_u(const f32x16& a, uint4& b0, uint4& b1) {
  unsigned p00 = pkmax0(pk2(a[0],  a[1]));
  unsigned p10 = pkmax0(pk2(a[2],  a[3]));
  unsigned p01 = pkmax0(pk2(a[4],  a[5]));
  unsigned p11 = pkmax0(pk2(a[6],  a[7]));
  unsigned p02 = pkmax0(pk2(a[8],  a[9]));
  unsigned p12 = pkmax0(pk2(a[10], a[11]));
  unsigned p03 = pkmax0(pk2(a[12], a[13]));
  unsigned p13 = pkmax0(pk2(a[14], a[15]));
  asm("v_permlane32_swap_b32 %0, %1" : "+v"(p00), "+v"(p01));
  asm("v_permlane32_swap_b32 %0, %1" : "+v"(p10), "+v"(p11));
  b0 = make_uint4(p00, p10, p01, p11);
  asm("v_permlane32_swap_b32 %0, %1" : "+v"(p02), "+v"(p03));
  asm("v_permlane32_swap_b32 %0, %1" : "+v"(p12), "+v"(p13));
  b1 = make_uint4(p02, p12, p03, p13);
}

// one hidden 96x96 layer for one 32-window tile. Only ONE 16-reg acc live at
// a time (per-u transition) -> small register footprint; u0's VALU overlaps
// u1's MFMA chain.
__device__ __forceinline__ void hidden_layer_t(const uint4* __restrict__ src, int lane,
                                               uint4 (&B)[6]) {
  uint4 Bn[6];
#pragma unroll
  for (int u = 0; u < 3; ++u) {
    f32x16 a = (f32x16)(0.f);
#pragma unroll
    for (int ks = 0; ks < 6; ++ks) {
      FragU Af; Af.u = src[(u * 6 + ks) * 64 + lane];
      a = __builtin_amdgcn_mfma_f32_32x32x16_f16(
            Af.h, __builtin_bit_cast(half8, B[ks]), a, 0, 0, 0);
    }
    trans_u(a, Bn[2 * u], Bn[2 * u + 1]);
  }
#pragma unroll
  for (int i = 0; i < 6; ++i) B[i] = Bn[i];
}

// ---------------- main kernel ----------------
// NOTE (measured R5/R6): launch_bounds min-waves caps VGPR at 256/min_waves;
// min=4 -> 64 regs -> 1.1 GB spill. Keep min=2. Occupancy has been pinned at
// ~17% (= ~2 waves/SIMD) across all configs; working theory is the unified
// VGPR+AGPR total (~200) is the cap, hence this round's per-u acc structure.
__global__ __launch_bounds__(512, 2)
void dnpu_mfma(const float* __restrict__ x, const float* __restrict__ cv,
               const uint4* __restrict__ frags, float* __restrict__ out) {
  __shared__ uint4 lfr[72 * 64];             // layers 2-5 frags, 73,728 B
  const int tid  = threadIdx.x;
  const int lane = tid & 63, wid = tid >> 6;
  const int g = lane >> 5, c = lane & 31;
  const int b = blockIdx.y;

  // stage layers 2-5 weight frags to LDS once per block (8 waves share them)
  for (int i = tid; i < 72 * 64; i += 512) lfr[i] = frags[3 * 64 + i];
  __syncthreads();

  const float c0 = cv[0], c1 = cv[1], c2 = cv[2], c3 = cv[3];
  const float* xr = x + (size_t)b * LSEQ;
  const int rowbase0 = blockIdx.x * (NTILE * 32 * 8) + wid * (NTILE * 32);

  uint4 Bw[NTILE][6];   // per-tile activation B-frags (current layer's input)

  // ---- layer 1: K padded to 16; g=0 lanes hold [c0,c1,x0,x1,x2,c2,c3,1] ----
#pragma unroll
  for (int t = 0; t < NTILE; ++t) {
    const int w  = rowbase0 + t * 32 + c;
    const int xi = (w < LSEQ - 3) ? w : (LSEQ - 3);
    const float x0 = xr[xi], x1 = xr[xi + 1], x2 = xr[xi + 2];
    half8 B1;
#pragma unroll
    for (int i = 0; i < 8; ++i) B1[i] = (_Float16)0.f;
    if (g == 0) {
      B1[0] = (_Float16)c0; B1[1] = (_Float16)c1;
      B1[2] = (_Float16)x0; B1[3] = (_Float16)x1; B1[4] = (_Float16)x2;
      B1[5] = (_Float16)c2; B1[6] = (_Float16)c3; B1[7] = (_Float16)1.0f;
    }
#pragma unroll
    for (int t2 = 0; t2 < 3; ++t2) {
      FragU Af; Af.u = frags[t2 * 64 + lane];
      f32x16 a = __builtin_amdgcn_mfma_f32_32x32x16_f16(Af.h, B1, (f32x16)(0.f), 0, 0, 0);
      trans_u(a, Bw[t][2 * t2], Bw[t][2 * t2 + 1]);
    }
  }

  // ---- layers 2..5 from LDS ----
#pragma unroll
  for (int t = 0; t < NTILE; ++t) hidden_layer_t(&lfr[0 * 18 * 64], lane, Bw[t]);  // L2
#pragma unroll
  for (int t = 0; t < NTILE; ++t) hidden_layer_t(&lfr[1 * 18 * 64], lane, Bw[t]);  // L3
#pragma unroll
  for (int t = 0; t < NTILE; ++t) hidden_layer_t(&lfr[2 * 18 * 64], lane, Bw[t]);  // L4
#pragma unroll
  for (int t = 0; t < NTILE; ++t) hidden_layer_t(&lfr[3 * 18 * 64], lane, Bw[t]);  // L5

  // ---- layer 6: 96 -> 1 (row 0 of n-tile 0), then * AMP ----
#pragma unroll
  for (int t = 0; t < NTILE; ++t) {
    f32x16 a = (f32x16)(0.f);
#pragma unroll
    for (int ks = 0; ks < 6; ++ks) {
      FragU Af; Af.u = frags[(75 + ks) * 64 + lane];
      a = __builtin_amdgcn_mfma_f32_32x32x16_f16(
            Af.h, __builtin_bit_cast(half8, Bw[t][ks]), a, 0, 0, 0);
    }
    if (g == 0) {
      const int row = rowbase0 + t * 32 + c;
      if (row < NW) out[(size_t)b * NW + row] = a[0] * AMPF;
    }
  }
}

extern "C" void kernel_launch(void* const* d_in, const int* in_sizes, int n_in,
                              void* d_out, int out_size, void* d_ws, size_t ws_size,
                              hipStream_t stream) {
  const float* x  = (const float*)d_in[0];
  const float* cv = (const float*)d_in[1];
  const float* W1 = (const float*)d_in[2];
  const float* b1 = (const float*)d_in[3];
  const float* W2 = (const float*)d_in[4];
  const float* b2 = (const float*)d_in[5];
  const float* W3 = (const float*)d_in[6];
  const float* b3 = (const float*)d_in[7];
  const float* W4 = (const float*)d_in[8];
  const float* b4 = (const float*)d_in[9];
  const float* W5 = (const float*)d_in[10];
  const float* b5 = (const float*)d_in[11];
  const float* W6 = (const float*)d_in[12];
  const float* b6 = (const float*)d_in[13];
  float* out = (float*)d_out;
  uint4* frags = (uint4*)d_ws;   // 81 * 64 * 16 B = 82,944 B

  hipLaunchKernelGGL(dnpu_pack, dim3(21), dim3(256), 0, stream,
                     W1, b1, W2, b2, W3, b3, W4, b4, W5, b5, W6, b6, frags);
  // 8192 windows: 16 blocks x (8 waves * 64 windows)
  hipLaunchKernelGGL(dnpu_mfma, dim3(16, NB), dim3(512), 0, stream,
                     x, cv, frags, out);
}

// Round 11
// 44.473 us; speedup vs baseline: 6.1823x; 1.0477x over previous
//
#include <hip/hip_runtime.h>

#define NB   64
#define LSEQ 8192
#define NW   8190
#define HD   90
#define AMPF 28.5f
#define NTILE 4

typedef _Float16 half8  __attribute__((ext_vector_type(8)));
typedef float    f32x16 __attribute__((ext_vector_type(16)));
typedef __fp16   fp16x2 __attribute__((ext_vector_type(2)));

union FragU { uint4 u; half8 h; };

__device__ __forceinline__ unsigned pk2(float a, float b) {
  fp16x2 v = __builtin_amdgcn_cvt_pkrtz(a, b);
  return __builtin_bit_cast(unsigned, v);
}
// packed ReLU on 2xfp16
__device__ __forceinline__ unsigned pkmax0(unsigned w) {
  unsigned r;
  asm("v_pk_max_f16 %0, %1, %2" : "=v"(r) : "v"(w), "v"(0u));
  return r;
}

// ---------------- weight fragment pre-pack (A-operand, swapped formulation) ----
// D[n][w] = sum_k W[k][n] * H[k][w].  A-frag layout (mfma_f32_32x32x16_f16):
//   lane l: row n = 32*t2 + (l&31);  k = 16*ks + 8*(l>>5) + i   (i = 0..7)
// ids: 0..2   layer1  (t2 = f, ks = 0; kin=7, k==7 -> b1)
//      3..74  layers2-5 (f = 3 + L*18 + t2*6 + ks; kin=90, k==90 -> bias)
//      75..80 layer6  (ks = f-75; nout=1: only row n==0 nonzero)
// Bias-propagation: for layers 1..5, A[k==kin][n==90] = 1.0 so that output
// row 90 == 1.0 for every window; it survives relu+pack exactly, and serves
// as the bias activation (k=90) for the next layer. No per-tile fixup needed.
__global__ void dnpu_pack(const float* __restrict__ W1, const float* __restrict__ b1,
                          const float* __restrict__ W2, const float* __restrict__ b2,
                          const float* __restrict__ W3, const float* __restrict__ b3,
                          const float* __restrict__ W4, const float* __restrict__ b4,
                          const float* __restrict__ W5, const float* __restrict__ b5,
                          const float* __restrict__ W6, const float* __restrict__ b6,
                          uint4* __restrict__ frags) {
  int tid = blockIdx.x * blockDim.x + threadIdx.x;
  if (tid >= 81 * 64) return;
  int f = tid >> 6, lane = tid & 63;
  int n = lane & 31, g = lane >> 5;
  const float* W; const float* bias; int t2, ks, kin, nout;
  if (f < 3) {
    W = W1; bias = b1; t2 = f; ks = 0; kin = 7; nout = HD;
  } else if (f < 75) {
    int q = f - 3; int L = q / 18; int r = q % 18;
    t2 = r / 6; ks = r % 6; kin = HD; nout = HD;
    W    = (L == 0) ? W2 : (L == 1) ? W3 : (L == 2) ? W4 : W5;
    bias = (L == 0) ? b2 : (L == 1) ? b3 : (L == 2) ? b4 : b5;
  } else {
    W = W6; bias = b6; t2 = 0; ks = f - 75; kin = HD; nout = 1;
  }
  int row = 32 * t2 + n;
  FragU u;
#pragma unroll
  for (int i = 0; i < 8; ++i) {
    int k = 16 * ks + 8 * g + i;
    float val = 0.f;
    if (row < nout) {
      if (k < kin)       val = W[k * nout + row];
      else if (k == kin) val = bias[row];
    }
    if (row == HD && k == kin && f < 75) val = 1.0f;  // bias-propagation row
    u.h[i] = (_Float16)val;
  }
  frags[f * 64 + lane] = u.u;
}

// ---- per-u transition: one 32x96 acc slice -> two next-layer B-frags ----
// C: lane l holds col w = l&31, row n = 32*u + (r&3) + 8*(r>>2) + 4*(l>>5).
// B-frag[ks=2u+par]: lane l needs col w = l&31 (same lane), k' = n.
// Pack n-consecutive fp16 pairs (ReLU via pk_max post-pack), then one
// permlane32_swap per word pair so each lane holds its full i0..7 run.
__device__ __forceinline__ void trans_u(const f32x16& a, uint4& b0, uint4& b1) {
  unsigned p00 = pkmax0(pk2(a[0],  a[1]));
  unsigned p10 = pkmax0(pk2(a[2],  a[3]));
  unsigned p01 = pkmax0(pk2(a[4],  a[5]));
  unsigned p11 = pkmax0(pk2(a[6],  a[7]));
  unsigned p02 = pkmax0(pk2(a[8],  a[9]));
  unsigned p12 = pkmax0(pk2(a[10], a[11]));
  unsigned p03 = pkmax0(pk2(a[12], a[13]));
  unsigned p13 = pkmax0(pk2(a[14], a[15]));
  asm("v_permlane32_swap_b32 %0, %1" : "+v"(p00), "+v"(p01));
  asm("v_permlane32_swap_b32 %0, %1" : "+v"(p10), "+v"(p11));
  b0 = make_uint4(p00, p10, p01, p11);
  asm("v_permlane32_swap_b32 %0, %1" : "+v"(p02), "+v"(p03));
  asm("v_permlane32_swap_b32 %0, %1" : "+v"(p12), "+v"(p13));
  b1 = make_uint4(p02, p12, p03, p13);
}

// one hidden 96x96 layer across ALL NTILE tiles: for each u-block, the NTILE
// tiles give NTILE independent 6-deep MFMA chains (issue 8cyc x NTILE covers
// MFMA latency within one wave), then per-tile transitions.
__device__ __forceinline__ void hidden_layer(const uint4* __restrict__ src, int lane,
                                             uint4 (&Bw)[NTILE][6]) {
  uint4 Bn[NTILE][6];
#pragma unroll
  for (int u = 0; u < 3; ++u) {
    f32x16 a[NTILE];
#pragma unroll
    for (int t = 0; t < NTILE; ++t) a[t] = (f32x16)(0.f);
#pragma unroll
    for (int ks = 0; ks < 6; ++ks) {
      FragU Af; Af.u = src[(u * 6 + ks) * 64 + lane];
#pragma unroll
      for (int t = 0; t < NTILE; ++t)
        a[t] = __builtin_amdgcn_mfma_f32_32x32x16_f16(
                 Af.h, __builtin_bit_cast(half8, Bw[t][ks]), a[t], 0, 0, 0);
    }
#pragma unroll
    for (int t = 0; t < NTILE; ++t) trans_u(a[t], Bn[t][2 * u], Bn[t][2 * u + 1]);
  }
#pragma unroll
  for (int t = 0; t < NTILE; ++t)
#pragma unroll
    for (int i = 0; i < 6; ++i) Bw[t][i] = Bn[t][i];
}

// ---------------- main kernel ----------------
// NOTE (measured R5/R6): launch_bounds min-waves caps VGPR at 256/min_waves;
// min=4 -> 64 regs -> 1.1 GB spill. Keep min=2. R8-R10: dur invariant to
// VGPR/LDS/block-size at NTILE=2 -> this round tests per-wave ILP (NTILE=4).
__global__ __launch_bounds__(512, 2)
void dnpu_mfma(const float* __restrict__ x, const float* __restrict__ cv,
               const uint4* __restrict__ frags, float* __restrict__ out) {
  __shared__ uint4 lfr[72 * 64];             // layers 2-5 frags, 73,728 B
  const int tid  = threadIdx.x;
  const int lane = tid & 63, wid = tid >> 6;
  const int g = lane >> 5, c = lane & 31;
  const int b = blockIdx.y;

  // stage layers 2-5 weight frags to LDS once per block (8 waves share them)
  for (int i = tid; i < 72 * 64; i += 512) lfr[i] = frags[3 * 64 + i];
  __syncthreads();

  const float c0 = cv[0], c1 = cv[1], c2 = cv[2], c3 = cv[3];
  const float* xr = x + (size_t)b * LSEQ;
  const int rowbase0 = blockIdx.x * (NTILE * 32 * 8) + wid * (NTILE * 32);

  uint4 Bw[NTILE][6];   // per-tile activation B-frags (current layer's input)

  // ---- layer 1: K padded to 16; g=0 lanes hold [c0,c1,x0,x1,x2,c2,c3,1] ----
#pragma unroll
  for (int t = 0; t < NTILE; ++t) {
    const int w  = rowbase0 + t * 32 + c;
    const int xi = (w < LSEQ - 3) ? w : (LSEQ - 3);
    const float x0 = xr[xi], x1 = xr[xi + 1], x2 = xr[xi + 2];
    half8 B1;
#pragma unroll
    for (int i = 0; i < 8; ++i) B1[i] = (_Float16)0.f;
    if (g == 0) {
      B1[0] = (_Float16)c0; B1[1] = (_Float16)c1;
      B1[2] = (_Float16)x0; B1[3] = (_Float16)x1; B1[4] = (_Float16)x2;
      B1[5] = (_Float16)c2; B1[6] = (_Float16)c3; B1[7] = (_Float16)1.0f;
    }
#pragma unroll
    for (int t2 = 0; t2 < 3; ++t2) {
      FragU Af; Af.u = frags[t2 * 64 + lane];
      f32x16 a = __builtin_amdgcn_mfma_f32_32x32x16_f16(Af.h, B1, (f32x16)(0.f), 0, 0, 0);
      trans_u(a, Bw[t][2 * t2], Bw[t][2 * t2 + 1]);
    }
  }

  // ---- layers 2..5 from LDS; NTILE independent chains per u-block ----
  hidden_layer(&lfr[0 * 18 * 64], lane, Bw);   // L2
  hidden_layer(&lfr[1 * 18 * 64], lane, Bw);   // L3
  hidden_layer(&lfr[2 * 18 * 64], lane, Bw);   // L4
  hidden_layer(&lfr[3 * 18 * 64], lane, Bw);   // L5

  // ---- layer 6: 96 -> 1 (row 0 of n-tile 0), then * AMP ----
  {
    FragU Af6[6];
#pragma unroll
    for (int ks = 0; ks < 6; ++ks) Af6[ks].u = frags[(75 + ks) * 64 + lane];
#pragma unroll
    for (int t = 0; t < NTILE; ++t) {
      f32x16 a = (f32x16)(0.f);
#pragma unroll
      for (int ks = 0; ks < 6; ++ks)
        a = __builtin_amdgcn_mfma_f32_32x32x16_f16(
              Af6[ks].h, __builtin_bit_cast(half8, Bw[t][ks]), a, 0, 0, 0);
      if (g == 0) {
        const int row = rowbase0 + t * 32 + c;
        if (row < NW) out[(size_t)b * NW + row] = a[0] * AMPF;
      }
    }
  }
}

extern "C" void kernel_launch(void* const* d_in, const int* in_sizes, int n_in,
                              void* d_out, int out_size, void* d_ws, size_t ws_size,
                              hipStream_t stream) {
  const float* x  = (const float*)d_in[0];
  const float* cv = (const float*)d_in[1];
  const float* W1 = (const float*)d_in[2];
  const float* b1 = (const float*)d_in[3];
  const float* W2 = (const float*)d_in[4];
  const float* b2 = (const float*)d_in[5];
  const float* W3 = (const float*)d_in[6];
  const float* b3 = (const float*)d_in[7];
  const float* W4 = (const float*)d_in[8];
  const float* b4 = (const float*)d_in[9];
  const float* W5 = (const float*)d_in[10];
  const float* b5 = (const float*)d_in[11];
  const float* W6 = (const float*)d_in[12];
  const float* b6 = (const float*)d_in[13];
  float* out = (float*)d_out;
  uint4* frags = (uint4*)d_ws;   // 81 * 64 * 16 B = 82,944 B

  hipLaunchKernelGGL(dnpu_pack, dim3(21), dim3(256), 0, stream,
                     W1, b1, W2, b2, W3, b3, W4, b4, W5, b5, W6, b6, frags);
  // 8192 windows: 8 blocks x (8 waves * 128 windows)
  hipLaunchKernelGGL(dnpu_mfma, dim3(8, NB), dim3(512), 0, stream,
                     x, cv, frags, out);
}